// Round 1
// baseline (615.697 us; speedup 1.0000x reference)
//
#include <hip/hip_runtime.h>

typedef _Float16 f16;
typedef _Float16 f16x8 __attribute__((ext_vector_type(8)));
typedef _Float16 f16x4 __attribute__((ext_vector_type(4)));
typedef float f32x4 __attribute__((ext_vector_type(4)));

constexpr int NB = 32, NS = 576, ND = 768, NG = 24;
constexpr int M_TOT = NB * NS;   // 18432
constexpr int N_TOT = 3 * ND;    // 2304

// ---------------- kernel 1: cast x (fp32 -> f16) ----------------
__global__ void cast_x_kernel(const float* __restrict__ x, f16* __restrict__ xb) {
  int i = (blockIdx.x * 256 + threadIdx.x) * 4;
  float4 v = *(const float4*)(x + i);
  f16x4 o;
  o.x = (f16)v.x; o.y = (f16)v.y; o.z = (f16)v.z; o.w = (f16)v.w;
  *(f16x4*)(xb + i) = o;
}

// ---------------- kernel 2: build W_allT (N_TOT x ND), f16, transposed ----------------
// WT[n][k] = W{q,k,v}[k][n%768]
__global__ void cast_w_kernel(const float* __restrict__ Wq, const float* __restrict__ Wk,
                              const float* __restrict__ Wv, f16* __restrict__ WT) {
  int t = blockIdx.x * 256 + threadIdx.x;   // 0 .. 2304*768-1
  int n = t / ND, k = t % ND;
  const float* src = (n >= 2 * ND) ? Wv : ((n >= ND) ? Wk : Wq);
  int nn = (n >= 2 * ND) ? n - 2 * ND : ((n >= ND) ? n - ND : n);
  WT[t] = (f16)src[k * ND + nn];
}

// ---------------- kernel 3: Wc = Wq@W1a + Wk@W1b (fp32), bc ----------------
// Wc[r][c], r in [0,768), c in [0,60). blocks 0..179 for Wc, block 180 for bc.
__global__ void wc_kernel(const float* __restrict__ Wq, const float* __restrict__ Wk,
                          const float* __restrict__ bq, const float* __restrict__ bk,
                          const float* __restrict__ W1, const float* __restrict__ b1,
                          float* __restrict__ Wc, float* __restrict__ bc) {
  if (blockIdx.x == 180) {
    int c = threadIdx.x;
    if (c < 60) {
      float acc = b1[c];
      for (int j = 0; j < ND; j++)
        acc += bq[j] * W1[j * 60 + c] + bk[j] * W1[(ND + j) * 60 + c];
      bc[c] = acc;
    }
    return;
  }
  int t = blockIdx.x * 256 + threadIdx.x;   // 0..46079
  int r = t / 60, c = t % 60;
  float acc = 0.f;
  for (int j = 0; j < ND; j++)
    acc += Wq[r * ND + j] * W1[j * 60 + c] + Wk[r * ND + j] * W1[(ND + j) * 60 + c];
  Wc[r * 60 + c] = acc;
}

// ---------------- kernel 4: GEMM qkv = x_f16 @ [Wq|Wk|Wv]_f16, f32 acc, f16 out ----------------
__device__ __forceinline__ void async_copy16(const f16* g, f16* l) {
  __builtin_amdgcn_global_load_lds((const __attribute__((address_space(1))) void*)g,
                                   (__attribute__((address_space(3))) void*)l, 16, 0, 0);
}

__global__ __launch_bounds__(256) void gemm_kernel(const f16* __restrict__ A,   // M_TOT x 768
                                                   const f16* __restrict__ Bt,  // 2304 x 768
                                                   const float* __restrict__ bq,
                                                   const float* __restrict__ bk,
                                                   const float* __restrict__ bv,
                                                   f16* __restrict__ C) {       // M_TOT x 2304
  constexpr int BM = 128, BN = 128, BK = 32;
  __shared__ __align__(16) f16 sA[BM * BK];
  __shared__ __align__(16) f16 sB[BN * BK];

  int bm = blockIdx.x % (M_TOT / BM);
  int bn = blockIdx.x / (M_TOT / BM);
  int tid = threadIdx.x;
  int wave = tid >> 6, lane = tid & 63;
  int wm = (wave >> 1) * 64, wn = (wave & 1) * 64;
  int m0 = bm * BM, n0 = bn * BN;

  int srow = tid >> 2;            // 0..63
  int skc = (tid & 3) * 8;        // k element offset of this thread's 16B chunk

  f32x4 acc[4][4];
#pragma unroll
  for (int i = 0; i < 4; i++)
#pragma unroll
    for (int j = 0; j < 4; j++) acc[i][j] = 0.f;

  int q = lane >> 4, r16 = lane & 15;

  for (int kk = 0; kk < ND; kk += BK) {
    async_copy16(A + (size_t)(m0 + srow) * ND + kk + skc, sA + tid * 8);
    async_copy16(A + (size_t)(m0 + 64 + srow) * ND + kk + skc, sA + 2048 + tid * 8);
    async_copy16(Bt + (size_t)(n0 + srow) * ND + kk + skc, sB + tid * 8);
    async_copy16(Bt + (size_t)(n0 + 64 + srow) * ND + kk + skc, sB + 2048 + tid * 8);
    __syncthreads();

    f16x8 aF[4], bF[4];
#pragma unroll
    for (int mt = 0; mt < 4; mt++)
      aF[mt] = *(const f16x8*)(sA + (wm + mt * 16 + r16) * BK + q * 8);
#pragma unroll
    for (int nt = 0; nt < 4; nt++)
      bF[nt] = *(const f16x8*)(sB + (wn + nt * 16 + r16) * BK + q * 8);
#pragma unroll
    for (int mt = 0; mt < 4; mt++)
#pragma unroll
      for (int nt = 0; nt < 4; nt++)
        acc[mt][nt] = __builtin_amdgcn_mfma_f32_16x16x32_f16(aF[mt], bF[nt], acc[mt][nt], 0, 0, 0);
    __syncthreads();
  }

#pragma unroll
  for (int nt = 0; nt < 4; nt++) {
    int gn = n0 + wn + nt * 16 + r16;
    float bias = (gn < ND) ? bq[gn] : ((gn < 2 * ND) ? bk[gn - ND] : bv[gn - 2 * ND]);
#pragma unroll
    for (int mt = 0; mt < 4; mt++) {
#pragma unroll
      for (int r = 0; r < 4; r++) {
        int gm = m0 + wm + mt * 16 + q * 4 + r;
        C[(size_t)gm * N_TOT + gn] = (f16)(acc[mt][nt][r] + bias);
      }
    }
  }
}

// ---------------- kernel 5: z1 = relu(x @ Wc + bc), fp32, thread-per-row ----------------
__global__ __launch_bounds__(256, 1) void z1_kernel(const float* __restrict__ x,
                                                    const float* __restrict__ Wc,
                                                    const float* __restrict__ bc,
                                                    float* __restrict__ h1) {
  int m = blockIdx.x * 256 + threadIdx.x;
  const float* xr = x + (size_t)m * ND;
  float acc[60];
#pragma unroll
  for (int c = 0; c < 60; c++) acc[c] = bc[c];
  for (int j = 0; j < ND; j += 4) {
    float4 xv = *(const float4*)(xr + j);
    const float* w0 = Wc + (size_t)j * 60;
#pragma unroll
    for (int c = 0; c < 60; c++) acc[c] = fmaf(xv.x, w0[c], acc[c]);
#pragma unroll
    for (int c = 0; c < 60; c++) acc[c] = fmaf(xv.y, w0[60 + c], acc[c]);
#pragma unroll
    for (int c = 0; c < 60; c++) acc[c] = fmaf(xv.z, w0[120 + c], acc[c]);
#pragma unroll
    for (int c = 0; c < 60; c++) acc[c] = fmaf(xv.w, w0[180 + c], acc[c]);
  }
  float* o = h1 + (size_t)m * 60;
#pragma unroll
  for (int c = 0; c < 60; c++) o[c] = fmaxf(acc[c], 0.f);
}

// ---------------- kernel 6: layers 2,3 + tanh + coord scatter; wave-per-row ----------------
__global__ void mlp_tail_kernel(const float* __restrict__ h1, const float* __restrict__ W2,
                                const float* __restrict__ b2, const float* __restrict__ W3,
                                const float* __restrict__ b3, float* __restrict__ coords) {
  int m = (blockIdx.x * 256 + threadIdx.x) >> 6;   // row
  int lane = threadIdx.x & 63;
  int cl = (lane < 60) ? lane : 59;
  const float* h = h1 + (size_t)m * 60;
  float acc = b2[cl];
  for (int j = 0; j < 60; j++) acc = fmaf(h[j], W2[j * 60 + cl], acc);
  float h2 = fmaxf(acc, 0.f);
  float p0 = (lane < 60) ? h2 * W3[cl * 2 + 0] : 0.f;
  float p1 = (lane < 60) ? h2 * W3[cl * 2 + 1] : 0.f;
#pragma unroll
  for (int o = 32; o > 0; o >>= 1) { p0 += __shfl_down(p0, o); p1 += __shfl_down(p1, o); }
  if (lane == 0) {
    float s0 = tanhf(p0 + b3[0]);
    float s1 = tanhf(p1 + b3[1]);
    int b = m / NS, s = m % NS;
    float* cb = coords + (size_t)b * (2 * NS);
    // sample[.,s,0] -> flat idx s   -> point s>>1,       channel s&1
    // sample[.,s,1] -> flat idx S+s -> point 288+(s>>1), channel s&1
    cb[(s >> 1) * 2 + (s & 1)] = s0;
    cb[(288 + (s >> 1)) * 2 + (s & 1)] = s1;
  }
}

// ---------------- kernel 7: bilinear sample + score + sigmoid*value ----------------
__global__ __launch_bounds__(256) void sample_kernel(const f16* __restrict__ qkv,
                                                     const float* __restrict__ coords,
                                                     float* __restrict__ out) {
  int blk = blockIdx.x;            // 0..18431
  int b = blk / NS, p = blk % NS;
  int tid = threadIdx.x;

  float gx = coords[(size_t)b * (2 * NS) + p * 2 + 0];
  float gy = coords[(size_t)b * (2 * NS) + p * 2 + 1];
  float ix = ((gx + 1.f) * (float)NG - 1.f) * 0.5f;
  float iy = ((gy + 1.f) * (float)NG - 1.f) * 0.5f;
  float x0f = floorf(ix), y0f = floorf(iy);
  float wx1 = ix - x0f, wx0 = 1.f - wx1;
  float wy1 = iy - y0f, wy0 = 1.f - wy1;
  int x0 = (int)x0f, y0 = (int)y0f, x1 = x0 + 1, y1 = y0 + 1;
  bool vx0 = (x0 >= 0) & (x0 <= NG - 1), vx1 = (x1 >= 0) & (x1 <= NG - 1);
  bool vy0 = (y0 >= 0) & (y0 <= NG - 1), vy1 = (y1 >= 0) & (y1 <= NG - 1);
  int cx0 = min(max(x0, 0), NG - 1), cx1 = min(max(x1, 0), NG - 1);
  int cy0 = min(max(y0, 0), NG - 1), cy1 = min(max(y1, 0), NG - 1);
  float w00 = wx0 * wy0 * ((vx0 && vy0) ? 1.f : 0.f);
  float w10 = wx1 * wy0 * ((vx1 && vy0) ? 1.f : 0.f);
  float w01 = wx0 * wy1 * ((vx0 && vy1) ? 1.f : 0.f);
  float w11 = wx1 * wy1 * ((vx1 && vy1) ? 1.f : 0.f);

  size_t base = (size_t)b * NS;
  const f16* r00 = qkv + (base + cy0 * NG + cx0) * N_TOT;
  const f16* r10 = qkv + (base + cy0 * NG + cx1) * N_TOT;
  const f16* r01 = qkv + (base + cy1 * NG + cx0) * N_TOT;
  const f16* r11 = qkv + (base + cy1 * NG + cx1) * N_TOT;
  const f16* qr  = qkv + (base + p) * N_TOT;

  float partial = 0.f;
  float svs[3];
#pragma unroll
  for (int i = 0; i < 3; i++) {
    int d = tid + i * 256;
    float sk = w00 * (float)r00[ND + d] + w10 * (float)r10[ND + d]
             + w01 * (float)r01[ND + d] + w11 * (float)r11[ND + d];
    float sv = w00 * (float)r00[2 * ND + d] + w10 * (float)r10[2 * ND + d]
             + w01 * (float)r01[2 * ND + d] + w11 * (float)r11[2 * ND + d];
    partial = fmaf((float)qr[d], sk, partial);
    svs[i] = sv;
  }
  __shared__ float red[4];
#pragma unroll
  for (int o = 32; o > 0; o >>= 1) partial += __shfl_down(partial, o);
  if ((tid & 63) == 0) red[tid >> 6] = partial;
  __syncthreads();
  float score = red[0] + red[1] + red[2] + red[3];
  float sig = 1.f / (1.f + expf(-0.01f * score));
  float* orow = out + (size_t)(base + p) * ND;
#pragma unroll
  for (int i = 0; i < 3; i++) orow[tid + i * 256] = sig * svs[i];
}

extern "C" void kernel_launch(void* const* d_in, const int* in_sizes, int n_in,
                              void* d_out, int out_size, void* d_ws, size_t ws_size,
                              hipStream_t stream) {
  const float* x  = (const float*)d_in[0];
  // d_in[1] = indices (unused by reference)
  const float* Wq = (const float*)d_in[2];
  const float* bq = (const float*)d_in[3];
  const float* Wk = (const float*)d_in[4];
  const float* bk = (const float*)d_in[5];
  const float* Wv = (const float*)d_in[6];
  const float* bv = (const float*)d_in[7];
  const float* W1 = (const float*)d_in[8];
  const float* b1 = (const float*)d_in[9];
  const float* W2 = (const float*)d_in[10];
  const float* b2 = (const float*)d_in[11];
  const float* W3 = (const float*)d_in[12];
  const float* b3 = (const float*)d_in[13];
  float* out = (float*)d_out;

  char* ws = (char*)d_ws;
  f16*   xb     = (f16*)(ws);                       // 18432*768*2  = 28,311,552
  f16*   WT     = (f16*)(ws + 28311552);            // 2304*768*2   =  3,538,944
  f16*   qkv    = (f16*)(ws + 31850496);            // 18432*2304*2 = 84,934,656
  float* Wc     = (float*)(ws + 116785152);         // 768*60*4     =    184,320
  float* bc     = (float*)(ws + 116969472);         // 256
  float* h1     = (float*)(ws + 116969728);         // 18432*60*4   =  4,423,680
  float* coords = (float*)(ws + 121393408);         // 32*1152*4    =    147,456
  // total 121,540,864 bytes

  cast_x_kernel<<<dim3(M_TOT * ND / 1024), dim3(256), 0, stream>>>(x, xb);
  cast_w_kernel<<<dim3(N_TOT * ND / 256), dim3(256), 0, stream>>>(Wq, Wk, Wv, WT);
  wc_kernel<<<dim3(181), dim3(256), 0, stream>>>(Wq, Wk, bq, bk, W1, b1, Wc, bc);
  gemm_kernel<<<dim3((M_TOT / 128) * (N_TOT / 128)), dim3(256), 0, stream>>>(xb, WT, bq, bk, bv, qkv);
  z1_kernel<<<dim3(M_TOT / 256), dim3(256), 0, stream>>>(x, Wc, bc, h1);
  mlp_tail_kernel<<<dim3(M_TOT / 4), dim3(256), 0, stream>>>(h1, W2, b2, W3, b3, coords);
  sample_kernel<<<dim3(M_TOT), dim3(256), 0, stream>>>(qkv, coords, out);
  (void)in_sizes; (void)n_in; (void)out_size; (void)ws_size;
}

// Round 2
// 487.770 us; speedup vs baseline: 1.2623x; 1.2623x over previous
//
#include <hip/hip_runtime.h>

typedef _Float16 f16;
typedef _Float16 f16x8 __attribute__((ext_vector_type(8)));
typedef _Float16 f16x4 __attribute__((ext_vector_type(4)));
typedef float f32x4 __attribute__((ext_vector_type(4)));

constexpr int NB = 32, NS = 576, ND = 768, NG = 24;
constexpr int M_TOT = NB * NS;   // 18432
constexpr int N_TOT = 3 * ND;    // 2304

// ---------------- kernel 1: cast x (fp32 -> f16) ----------------
__global__ void cast_x_kernel(const float* __restrict__ x, f16* __restrict__ xb) {
  int i = (blockIdx.x * 256 + threadIdx.x) * 4;
  float4 v = *(const float4*)(x + i);
  f16x4 o;
  o.x = (f16)v.x; o.y = (f16)v.y; o.z = (f16)v.z; o.w = (f16)v.w;
  *(f16x4*)(xb + i) = o;
}

// ---------------- kernel 2: build W_allT (N_TOT x ND), f16, transposed ----------------
// WT[n][k] = W{q,k,v}[k][n%768]
__global__ void cast_w_kernel(const float* __restrict__ Wq, const float* __restrict__ Wk,
                              const float* __restrict__ Wv, f16* __restrict__ WT) {
  int t = blockIdx.x * 256 + threadIdx.x;   // 0 .. 2304*768-1
  int n = t / ND, k = t % ND;
  const float* src = (n >= 2 * ND) ? Wv : ((n >= ND) ? Wk : Wq);
  int nn = (n >= 2 * ND) ? n - 2 * ND : ((n >= ND) ? n - ND : n);
  WT[t] = (f16)src[k * ND + nn];
}

// ---------------- kernel 3: Wc = Wq@W1a + Wk@W1b (fp32), bc ----------------
__global__ void wc_kernel(const float* __restrict__ Wq, const float* __restrict__ Wk,
                          const float* __restrict__ bq, const float* __restrict__ bk,
                          const float* __restrict__ W1, const float* __restrict__ b1,
                          float* __restrict__ Wc, float* __restrict__ bc) {
  if (blockIdx.x == 180) {
    int c = threadIdx.x;
    if (c < 60) {
      float acc = b1[c];
      for (int j = 0; j < ND; j++)
        acc += bq[j] * W1[j * 60 + c] + bk[j] * W1[(ND + j) * 60 + c];
      bc[c] = acc;
    }
    return;
  }
  int t = blockIdx.x * 256 + threadIdx.x;   // 0..46079
  int r = t / 60, c = t % 60;
  float acc = 0.f;
  for (int j = 0; j < ND; j++)
    acc += Wq[r * ND + j] * W1[j * 60 + c] + Wk[r * ND + j] * W1[(ND + j) * 60 + c];
  Wc[r * 60 + c] = acc;
}

// ---------------- kernel 4: GEMM qkv = x_f16 @ [Wq|Wk|Wv]_f16, f32 acc, f16 out ----------------
__device__ __forceinline__ void async_copy16(const f16* g, f16* l) {
  __builtin_amdgcn_global_load_lds((const __attribute__((address_space(1))) void*)g,
                                   (__attribute__((address_space(3))) void*)l, 16, 0, 0);
}

__global__ __launch_bounds__(256) void gemm_kernel(const f16* __restrict__ A,   // M_TOT x 768
                                                   const f16* __restrict__ Bt,  // 2304 x 768
                                                   const float* __restrict__ bq,
                                                   const float* __restrict__ bk,
                                                   const float* __restrict__ bv,
                                                   f16* __restrict__ C) {       // M_TOT x 2304
  constexpr int BM = 128, BN = 128, BK = 32;
  __shared__ __align__(16) f16 sA[BM * BK];
  __shared__ __align__(16) f16 sB[BN * BK];

  int bm = blockIdx.x % (M_TOT / BM);
  int bn = blockIdx.x / (M_TOT / BM);
  int tid = threadIdx.x;
  int wave = tid >> 6, lane = tid & 63;
  int wm = (wave >> 1) * 64, wn = (wave & 1) * 64;
  int m0 = bm * BM, n0 = bn * BN;

  int srow = tid >> 2;            // 0..63
  int skc = (tid & 3) * 8;        // k element offset of this thread's 16B chunk

  f32x4 acc[4][4];
#pragma unroll
  for (int i = 0; i < 4; i++)
#pragma unroll
    for (int j = 0; j < 4; j++) acc[i][j] = 0.f;

  int q = lane >> 4, r16 = lane & 15;

  for (int kk = 0; kk < ND; kk += BK) {
    async_copy16(A + (size_t)(m0 + srow) * ND + kk + skc, sA + tid * 8);
    async_copy16(A + (size_t)(m0 + 64 + srow) * ND + kk + skc, sA + 2048 + tid * 8);
    async_copy16(Bt + (size_t)(n0 + srow) * ND + kk + skc, sB + tid * 8);
    async_copy16(Bt + (size_t)(n0 + 64 + srow) * ND + kk + skc, sB + 2048 + tid * 8);
    __syncthreads();

    f16x8 aF[4], bF[4];
#pragma unroll
    for (int mt = 0; mt < 4; mt++)
      aF[mt] = *(const f16x8*)(sA + (wm + mt * 16 + r16) * BK + q * 8);
#pragma unroll
    for (int nt = 0; nt < 4; nt++)
      bF[nt] = *(const f16x8*)(sB + (wn + nt * 16 + r16) * BK + q * 8);
#pragma unroll
    for (int mt = 0; mt < 4; mt++)
#pragma unroll
      for (int nt = 0; nt < 4; nt++)
        acc[mt][nt] = __builtin_amdgcn_mfma_f32_16x16x32_f16(aF[mt], bF[nt], acc[mt][nt], 0, 0, 0);
    __syncthreads();
  }

#pragma unroll
  for (int nt = 0; nt < 4; nt++) {
    int gn = n0 + wn + nt * 16 + r16;
    float bias = (gn < ND) ? bq[gn] : ((gn < 2 * ND) ? bk[gn - ND] : bv[gn - 2 * ND]);
#pragma unroll
    for (int mt = 0; mt < 4; mt++) {
#pragma unroll
      for (int r = 0; r < 4; r++) {
        int gm = m0 + wm + mt * 16 + q * 4 + r;
        C[(size_t)gm * N_TOT + gn] = (f16)(acc[mt][nt][r] + bias);
      }
    }
  }
}

// ---------------- kernel 5: z1 = relu(x @ Wc + bc), fp32 ----------------
// wave-per-8-rows, lane-per-column. x loads are wave-uniform (scalar cache);
// Wc loads are coalesced (lanes 0..59 read 240B contiguous).
__global__ __launch_bounds__(256) void z1_kernel(const float* __restrict__ x,
                                                 const float* __restrict__ Wc,
                                                 const float* __restrict__ bc,
                                                 float* __restrict__ h1) {
  int wave_u = __builtin_amdgcn_readfirstlane(threadIdx.x >> 6);
  int lane = threadIdx.x & 63;
  int c = (lane < 60) ? lane : 59;
  int row0 = blockIdx.x * 32 + wave_u * 8;   // 18432/32 = 576 blocks

  float acc[8];
  float bcv = bc[c];
#pragma unroll
  for (int r = 0; r < 8; r++) acc[r] = bcv;

  for (int kk = 0; kk < ND; kk += 4) {
    float wcv[4];
#pragma unroll
    for (int j = 0; j < 4; j++) wcv[j] = Wc[(kk + j) * 60 + c];
#pragma unroll
    for (int r = 0; r < 8; r++) {
      const float* xr = x + (size_t)(row0 + r) * ND + kk;
#pragma unroll
      for (int j = 0; j < 4; j++) acc[r] = fmaf(xr[j], wcv[j], acc[r]);
    }
  }

  if (lane < 60) {
#pragma unroll
    for (int r = 0; r < 8; r++)
      h1[(size_t)(row0 + r) * 60 + c] = fmaxf(acc[r], 0.f);
  }
}

// ---------------- kernel 6: layers 2,3 + tanh + coord scatter; wave-per-row ----------------
__global__ void mlp_tail_kernel(const float* __restrict__ h1, const float* __restrict__ W2,
                                const float* __restrict__ b2, const float* __restrict__ W3,
                                const float* __restrict__ b3, float* __restrict__ coords) {
  int m = (blockIdx.x * 256 + threadIdx.x) >> 6;   // row
  int lane = threadIdx.x & 63;
  int cl = (lane < 60) ? lane : 59;
  const float* h = h1 + (size_t)m * 60;
  float acc = b2[cl];
  for (int j = 0; j < 60; j++) acc = fmaf(h[j], W2[j * 60 + cl], acc);
  float h2 = fmaxf(acc, 0.f);
  float p0 = (lane < 60) ? h2 * W3[cl * 2 + 0] : 0.f;
  float p1 = (lane < 60) ? h2 * W3[cl * 2 + 1] : 0.f;
#pragma unroll
  for (int o = 32; o > 0; o >>= 1) { p0 += __shfl_down(p0, o); p1 += __shfl_down(p1, o); }
  if (lane == 0) {
    float s0 = tanhf(p0 + b3[0]);
    float s1 = tanhf(p1 + b3[1]);
    int b = m / NS, s = m % NS;
    float* cb = coords + (size_t)b * (2 * NS);
    cb[(s >> 1) * 2 + (s & 1)] = s0;
    cb[(288 + (s >> 1)) * 2 + (s & 1)] = s1;
  }
}

// ---------------- kernel 7: bilinear sample + score + sigmoid*value ----------------
__global__ __launch_bounds__(256) void sample_kernel(const f16* __restrict__ qkv,
                                                     const float* __restrict__ coords,
                                                     float* __restrict__ out) {
  int blk = blockIdx.x;            // 0..18431
  int b = blk / NS, p = blk % NS;
  int tid = threadIdx.x;

  float gx = coords[(size_t)b * (2 * NS) + p * 2 + 0];
  float gy = coords[(size_t)b * (2 * NS) + p * 2 + 1];
  float ix = ((gx + 1.f) * (float)NG - 1.f) * 0.5f;
  float iy = ((gy + 1.f) * (float)NG - 1.f) * 0.5f;
  float x0f = floorf(ix), y0f = floorf(iy);
  float wx1 = ix - x0f, wx0 = 1.f - wx1;
  float wy1 = iy - y0f, wy0 = 1.f - wy1;
  int x0 = (int)x0f, y0 = (int)y0f, x1 = x0 + 1, y1 = y0 + 1;
  bool vx0 = (x0 >= 0) & (x0 <= NG - 1), vx1 = (x1 >= 0) & (x1 <= NG - 1);
  bool vy0 = (y0 >= 0) & (y0 <= NG - 1), vy1 = (y1 >= 0) & (y1 <= NG - 1);
  int cx0 = min(max(x0, 0), NG - 1), cx1 = min(max(x1, 0), NG - 1);
  int cy0 = min(max(y0, 0), NG - 1), cy1 = min(max(y1, 0), NG - 1);
  float w00 = wx0 * wy0 * ((vx0 && vy0) ? 1.f : 0.f);
  float w10 = wx1 * wy0 * ((vx1 && vy0) ? 1.f : 0.f);
  float w01 = wx0 * wy1 * ((vx0 && vy1) ? 1.f : 0.f);
  float w11 = wx1 * wy1 * ((vx1 && vy1) ? 1.f : 0.f);

  size_t base = (size_t)b * NS;
  const f16* r00 = qkv + (base + cy0 * NG + cx0) * N_TOT;
  const f16* r10 = qkv + (base + cy0 * NG + cx1) * N_TOT;
  const f16* r01 = qkv + (base + cy1 * NG + cx0) * N_TOT;
  const f16* r11 = qkv + (base + cy1 * NG + cx1) * N_TOT;
  const f16* qr  = qkv + (base + p) * N_TOT;

  float partial = 0.f;
  float svs[3];
#pragma unroll
  for (int i = 0; i < 3; i++) {
    int d = tid + i * 256;
    float sk = w00 * (float)r00[ND + d] + w10 * (float)r10[ND + d]
             + w01 * (float)r01[ND + d] + w11 * (float)r11[ND + d];
    float sv = w00 * (float)r00[2 * ND + d] + w10 * (float)r10[2 * ND + d]
             + w01 * (float)r01[2 * ND + d] + w11 * (float)r11[2 * ND + d];
    partial = fmaf((float)qr[d], sk, partial);
    svs[i] = sv;
  }
  __shared__ float red[4];
#pragma unroll
  for (int o = 32; o > 0; o >>= 1) partial += __shfl_down(partial, o);
  if ((tid & 63) == 0) red[tid >> 6] = partial;
  __syncthreads();
  float score = red[0] + red[1] + red[2] + red[3];
  float sig = 1.f / (1.f + expf(-0.01f * score));
  float* orow = out + (size_t)(base + p) * ND;
#pragma unroll
  for (int i = 0; i < 3; i++) orow[tid + i * 256] = sig * svs[i];
}

extern "C" void kernel_launch(void* const* d_in, const int* in_sizes, int n_in,
                              void* d_out, int out_size, void* d_ws, size_t ws_size,
                              hipStream_t stream) {
  const float* x  = (const float*)d_in[0];
  const float* Wq = (const float*)d_in[2];
  const float* bq = (const float*)d_in[3];
  const float* Wk = (const float*)d_in[4];
  const float* bk = (const float*)d_in[5];
  const float* Wv = (const float*)d_in[6];
  const float* bv = (const float*)d_in[7];
  const float* W1 = (const float*)d_in[8];
  const float* b1 = (const float*)d_in[9];
  const float* W2 = (const float*)d_in[10];
  const float* b2 = (const float*)d_in[11];
  const float* W3 = (const float*)d_in[12];
  const float* b3 = (const float*)d_in[13];
  float* out = (float*)d_out;

  char* ws = (char*)d_ws;
  f16*   xb     = (f16*)(ws);                       // 28,311,552
  f16*   WT     = (f16*)(ws + 28311552);            //  3,538,944
  f16*   qkv    = (f16*)(ws + 31850496);            // 84,934,656
  float* Wc     = (float*)(ws + 116785152);         //    184,320
  float* bc     = (float*)(ws + 116969472);         //        256
  float* h1     = (float*)(ws + 116969728);         //  4,423,680
  float* coords = (float*)(ws + 121393408);         //    147,456

  cast_x_kernel<<<dim3(M_TOT * ND / 1024), dim3(256), 0, stream>>>(x, xb);
  cast_w_kernel<<<dim3(N_TOT * ND / 256), dim3(256), 0, stream>>>(Wq, Wk, Wv, WT);
  wc_kernel<<<dim3(181), dim3(256), 0, stream>>>(Wq, Wk, bq, bk, W1, b1, Wc, bc);
  gemm_kernel<<<dim3((M_TOT / 128) * (N_TOT / 128)), dim3(256), 0, stream>>>(xb, WT, bq, bk, bv, qkv);
  z1_kernel<<<dim3(M_TOT / 32), dim3(256), 0, stream>>>(x, Wc, bc, h1);
  mlp_tail_kernel<<<dim3(M_TOT / 4), dim3(256), 0, stream>>>(h1, W2, b2, W3, b3, coords);
  sample_kernel<<<dim3(M_TOT), dim3(256), 0, stream>>>(qkv, coords, out);
  (void)in_sizes; (void)n_in; (void)out_size; (void)ws_size;
}

// Round 3
// 411.267 us; speedup vs baseline: 1.4971x; 1.1860x over previous
//
#include <hip/hip_runtime.h>

typedef _Float16 f16;
typedef _Float16 f16x8 __attribute__((ext_vector_type(8)));
typedef _Float16 f16x4 __attribute__((ext_vector_type(4)));
typedef float f32x4 __attribute__((ext_vector_type(4)));

constexpr int NB = 32, NS = 576, ND = 768, NG = 24;
constexpr int M_TOT = NB * NS;   // 18432
constexpr int N_TOT = 3 * ND;    // 2304

// ---------------- kernel 1: cast x (fp32 -> f16) ----------------
__global__ void cast_x_kernel(const float* __restrict__ x, f16* __restrict__ xb) {
  int i = (blockIdx.x * 256 + threadIdx.x) * 4;
  float4 v = *(const float4*)(x + i);
  f16x4 o;
  o.x = (f16)v.x; o.y = (f16)v.y; o.z = (f16)v.z; o.w = (f16)v.w;
  *(f16x4*)(xb + i) = o;
}

// ---------------- kernel 2: build W_allT (N_TOT x ND), f16, transposed ----------------
__global__ void cast_w_kernel(const float* __restrict__ Wq, const float* __restrict__ Wk,
                              const float* __restrict__ Wv, f16* __restrict__ WT) {
  int t = blockIdx.x * 256 + threadIdx.x;   // 0 .. 2304*768-1
  int n = t / ND, k = t % ND;
  const float* src = (n >= 2 * ND) ? Wv : ((n >= ND) ? Wk : Wq);
  int nn = (n >= 2 * ND) ? n - 2 * ND : ((n >= ND) ? n - ND : n);
  WT[t] = (f16)src[k * ND + nn];
}

// ---------------- kernel 3: WcT hi/lo (f16 split of Wq@W1a + Wk@W1b), transposed [64][768]; bc ----
// blocks 0..191: one (r, c) per thread; lanes share r (scalar Wq/Wk loads), span c (coalesced W1).
// block 192: bc.
__global__ void wcT_kernel(const float* __restrict__ Wq, const float* __restrict__ Wk,
                           const float* __restrict__ bq, const float* __restrict__ bk,
                           const float* __restrict__ W1, const float* __restrict__ b1,
                           f16* __restrict__ WcT_hi, f16* __restrict__ WcT_lo,
                           float* __restrict__ bc) {
  if (blockIdx.x == 192) {
    int c = threadIdx.x;
    if (c < 60) {
      float acc = b1[c];
      for (int j = 0; j < ND; j++)
        acc += bq[j] * W1[j * 60 + c] + bk[j] * W1[(ND + j) * 60 + c];
      bc[c] = acc;
    }
    return;
  }
  int flat = blockIdx.x * 256 + threadIdx.x;   // 0..49151
  int r = flat >> 6, c = flat & 63;
  float acc = 0.f;
  if (c < 60) {
    const float* wq = Wq + (size_t)r * ND;
    const float* wk = Wk + (size_t)r * ND;
    for (int j = 0; j < ND; j++)
      acc += wq[j] * W1[j * 60 + c] + wk[j] * W1[(ND + j) * 60 + c];
  }
  f16 hi = (f16)acc;
  f16 lo = (f16)(acc - (float)hi);
  WcT_hi[(size_t)c * ND + r] = hi;
  WcT_lo[(size_t)c * ND + r] = lo;
}

// ---------------- kernel 4: GEMM qkv = x_f16 @ [Wq|Wk|Wv]_f16, f32 acc, f16 out ----------------
__device__ __forceinline__ void async_copy16(const f16* g, f16* l) {
  __builtin_amdgcn_global_load_lds((const __attribute__((address_space(1))) void*)g,
                                   (__attribute__((address_space(3))) void*)l, 16, 0, 0);
}

__global__ __launch_bounds__(256) void gemm_kernel(const f16* __restrict__ A,   // M_TOT x 768
                                                   const f16* __restrict__ Bt,  // 2304 x 768
                                                   const float* __restrict__ bq,
                                                   const float* __restrict__ bk,
                                                   const float* __restrict__ bv,
                                                   f16* __restrict__ C) {       // M_TOT x 2304
  constexpr int BM = 128, BN = 128, BK = 32;
  __shared__ __align__(16) f16 sA[BM * BK];
  __shared__ __align__(16) f16 sB[BN * BK];

  int bm = blockIdx.x % (M_TOT / BM);
  int bn = blockIdx.x / (M_TOT / BM);
  int tid = threadIdx.x;
  int wave = tid >> 6, lane = tid & 63;
  int wm = (wave >> 1) * 64, wn = (wave & 1) * 64;
  int m0 = bm * BM, n0 = bn * BN;

  int srow = tid >> 2;            // 0..63
  int skc = (tid & 3) * 8;        // k element offset of this thread's 16B chunk

  f32x4 acc[4][4];
#pragma unroll
  for (int i = 0; i < 4; i++)
#pragma unroll
    for (int j = 0; j < 4; j++) acc[i][j] = 0.f;

  int q = lane >> 4, r16 = lane & 15;

  for (int kk = 0; kk < ND; kk += BK) {
    async_copy16(A + (size_t)(m0 + srow) * ND + kk + skc, sA + tid * 8);
    async_copy16(A + (size_t)(m0 + 64 + srow) * ND + kk + skc, sA + 2048 + tid * 8);
    async_copy16(Bt + (size_t)(n0 + srow) * ND + kk + skc, sB + tid * 8);
    async_copy16(Bt + (size_t)(n0 + 64 + srow) * ND + kk + skc, sB + 2048 + tid * 8);
    __syncthreads();

    f16x8 aF[4], bF[4];
#pragma unroll
    for (int mt = 0; mt < 4; mt++)
      aF[mt] = *(const f16x8*)(sA + (wm + mt * 16 + r16) * BK + q * 8);
#pragma unroll
    for (int nt = 0; nt < 4; nt++)
      bF[nt] = *(const f16x8*)(sB + (wn + nt * 16 + r16) * BK + q * 8);
#pragma unroll
    for (int mt = 0; mt < 4; mt++)
#pragma unroll
      for (int nt = 0; nt < 4; nt++)
        acc[mt][nt] = __builtin_amdgcn_mfma_f32_16x16x32_f16(aF[mt], bF[nt], acc[mt][nt], 0, 0, 0);
    __syncthreads();
  }

#pragma unroll
  for (int nt = 0; nt < 4; nt++) {
    int gn = n0 + wn + nt * 16 + r16;
    float bias = (gn < ND) ? bq[gn] : ((gn < 2 * ND) ? bk[gn - ND] : bv[gn - 2 * ND]);
#pragma unroll
    for (int mt = 0; mt < 4; mt++) {
#pragma unroll
      for (int r = 0; r < 4; r++) {
        int gm = m0 + wm + mt * 16 + q * 4 + r;
        C[(size_t)gm * N_TOT + gn] = (f16)(acc[mt][nt][r] + bias);
      }
    }
  }
}

// ---------------- kernel 5: z1 = relu(x @ Wc + bc) via split-f16 MFMA ----------------
// wave-per-16-rows, no LDS. A from fp32 x (in-register hi/lo split), B frags from
// L2-resident WcT hi/lo. 3 MFMA terms: hi*hi + lo*hi + hi*lo  (~fp32 accuracy).
__global__ __launch_bounds__(256) void z1_mfma_kernel(const float* __restrict__ x,
                                                      const f16* __restrict__ WcT_hi,
                                                      const f16* __restrict__ WcT_lo,
                                                      const float* __restrict__ bc,
                                                      float* __restrict__ h1) {
  int wave = threadIdx.x >> 6, lane = threadIdx.x & 63;
  int q = lane >> 4, r16 = lane & 15;
  int m0 = blockIdx.x * 64 + wave * 16;          // 288 blocks
  const float* xr = x + (size_t)(m0 + r16) * ND; // this lane's A row

  f32x4 acc[4];
#pragma unroll
  for (int nf = 0; nf < 4; nf++) acc[nf] = 0.f;

  for (int kk = 0; kk < ND; kk += 32) {
    int ko = kk + q * 8;
    float4 v0 = *(const float4*)(xr + ko);
    float4 v1 = *(const float4*)(xr + ko + 4);
    f16x8 a_hi, a_lo;
    float xv[8] = {v0.x, v0.y, v0.z, v0.w, v1.x, v1.y, v1.z, v1.w};
#pragma unroll
    for (int j = 0; j < 8; j++) {
      f16 h = (f16)xv[j];
      a_hi[j] = h;
      a_lo[j] = (f16)(xv[j] - (float)h);
    }
    f16x8 b_hi[4], b_lo[4];
#pragma unroll
    for (int nf = 0; nf < 4; nf++) {
      size_t off = (size_t)(nf * 16 + r16) * ND + ko;
      b_hi[nf] = *(const f16x8*)(WcT_hi + off);
      b_lo[nf] = *(const f16x8*)(WcT_lo + off);
    }
#pragma unroll
    for (int nf = 0; nf < 4; nf++) {
      acc[nf] = __builtin_amdgcn_mfma_f32_16x16x32_f16(a_hi, b_hi[nf], acc[nf], 0, 0, 0);
      acc[nf] = __builtin_amdgcn_mfma_f32_16x16x32_f16(a_lo, b_hi[nf], acc[nf], 0, 0, 0);
      acc[nf] = __builtin_amdgcn_mfma_f32_16x16x32_f16(a_hi, b_lo[nf], acc[nf], 0, 0, 0);
    }
  }

#pragma unroll
  for (int nf = 0; nf < 4; nf++) {
    int col = nf * 16 + r16;
    if (col < 60) {
      float bcv = bc[col];
#pragma unroll
      for (int r = 0; r < 4; r++)
        h1[(size_t)(m0 + q * 4 + r) * 60 + col] = fmaxf(acc[nf][r] + bcv, 0.f);
    }
  }
}

// ---------------- kernel 6: layers 2,3 + tanh + coord scatter; wave-per-row ----------------
__global__ void mlp_tail_kernel(const float* __restrict__ h1, const float* __restrict__ W2,
                                const float* __restrict__ b2, const float* __restrict__ W3,
                                const float* __restrict__ b3, float* __restrict__ coords) {
  int m = (blockIdx.x * 256 + threadIdx.x) >> 6;   // row
  int lane = threadIdx.x & 63;
  int cl = (lane < 60) ? lane : 59;
  const float* h = h1 + (size_t)m * 60;
  float acc = b2[cl];
  for (int j = 0; j < 60; j++) acc = fmaf(h[j], W2[j * 60 + cl], acc);
  float h2 = fmaxf(acc, 0.f);
  float p0 = (lane < 60) ? h2 * W3[cl * 2 + 0] : 0.f;
  float p1 = (lane < 60) ? h2 * W3[cl * 2 + 1] : 0.f;
#pragma unroll
  for (int o = 32; o > 0; o >>= 1) { p0 += __shfl_down(p0, o); p1 += __shfl_down(p1, o); }
  if (lane == 0) {
    float s0 = tanhf(p0 + b3[0]);
    float s1 = tanhf(p1 + b3[1]);
    int b = m / NS, s = m % NS;
    float* cb = coords + (size_t)b * (2 * NS);
    cb[(s >> 1) * 2 + (s & 1)] = s0;
    cb[(288 + (s >> 1)) * 2 + (s & 1)] = s1;
  }
}

// ---------------- kernel 7: bilinear sample + score + sigmoid*value ----------------
__global__ __launch_bounds__(256) void sample_kernel(const f16* __restrict__ qkv,
                                                     const float* __restrict__ coords,
                                                     float* __restrict__ out) {
  int blk = blockIdx.x;            // 0..18431
  int b = blk / NS, p = blk % NS;
  int tid = threadIdx.x;

  float gx = coords[(size_t)b * (2 * NS) + p * 2 + 0];
  float gy = coords[(size_t)b * (2 * NS) + p * 2 + 1];
  float ix = ((gx + 1.f) * (float)NG - 1.f) * 0.5f;
  float iy = ((gy + 1.f) * (float)NG - 1.f) * 0.5f;
  float x0f = floorf(ix), y0f = floorf(iy);
  float wx1 = ix - x0f, wx0 = 1.f - wx1;
  float wy1 = iy - y0f, wy0 = 1.f - wy1;
  int x0 = (int)x0f, y0 = (int)y0f, x1 = x0 + 1, y1 = y0 + 1;
  bool vx0 = (x0 >= 0) & (x0 <= NG - 1), vx1 = (x1 >= 0) & (x1 <= NG - 1);
  bool vy0 = (y0 >= 0) & (y0 <= NG - 1), vy1 = (y1 >= 0) & (y1 <= NG - 1);
  int cx0 = min(max(x0, 0), NG - 1), cx1 = min(max(x1, 0), NG - 1);
  int cy0 = min(max(y0, 0), NG - 1), cy1 = min(max(y1, 0), NG - 1);
  float w00 = wx0 * wy0 * ((vx0 && vy0) ? 1.f : 0.f);
  float w10 = wx1 * wy0 * ((vx1 && vy0) ? 1.f : 0.f);
  float w01 = wx0 * wy1 * ((vx0 && vy1) ? 1.f : 0.f);
  float w11 = wx1 * wy1 * ((vx1 && vy1) ? 1.f : 0.f);

  size_t base = (size_t)b * NS;
  const f16* r00 = qkv + (base + cy0 * NG + cx0) * N_TOT;
  const f16* r10 = qkv + (base + cy0 * NG + cx1) * N_TOT;
  const f16* r01 = qkv + (base + cy1 * NG + cx0) * N_TOT;
  const f16* r11 = qkv + (base + cy1 * NG + cx1) * N_TOT;
  const f16* qr  = qkv + (base + p) * N_TOT;

  float partial = 0.f;
  float svs[3];
#pragma unroll
  for (int i = 0; i < 3; i++) {
    int d = tid + i * 256;
    float sk = w00 * (float)r00[ND + d] + w10 * (float)r10[ND + d]
             + w01 * (float)r01[ND + d] + w11 * (float)r11[ND + d];
    float sv = w00 * (float)r00[2 * ND + d] + w10 * (float)r10[2 * ND + d]
             + w01 * (float)r01[2 * ND + d] + w11 * (float)r11[2 * ND + d];
    partial = fmaf((float)qr[d], sk, partial);
    svs[i] = sv;
  }
  __shared__ float red[4];
#pragma unroll
  for (int o = 32; o > 0; o >>= 1) partial += __shfl_down(partial, o);
  if ((tid & 63) == 0) red[tid >> 6] = partial;
  __syncthreads();
  float score = red[0] + red[1] + red[2] + red[3];
  float sig = 1.f / (1.f + expf(-0.01f * score));
  float* orow = out + (size_t)(base + p) * ND;
#pragma unroll
  for (int i = 0; i < 3; i++) orow[tid + i * 256] = sig * svs[i];
}

extern "C" void kernel_launch(void* const* d_in, const int* in_sizes, int n_in,
                              void* d_out, int out_size, void* d_ws, size_t ws_size,
                              hipStream_t stream) {
  const float* x  = (const float*)d_in[0];
  const float* Wq = (const float*)d_in[2];
  const float* bq = (const float*)d_in[3];
  const float* Wk = (const float*)d_in[4];
  const float* bk = (const float*)d_in[5];
  const float* Wv = (const float*)d_in[6];
  const float* bv = (const float*)d_in[7];
  const float* W1 = (const float*)d_in[8];
  const float* b1 = (const float*)d_in[9];
  const float* W2 = (const float*)d_in[10];
  const float* b2 = (const float*)d_in[11];
  const float* W3 = (const float*)d_in[12];
  const float* b3 = (const float*)d_in[13];
  float* out = (float*)d_out;

  char* ws = (char*)d_ws;
  f16*   xb     = (f16*)(ws);                       // 28,311,552  (dead after gemm)
  f16*   WT     = (f16*)(ws + 28311552);            //  3,538,944
  f16*   qkv    = (f16*)(ws + 31850496);            // 84,934,656
  // WcT hi/lo live in the xb region (written after gemm has consumed xb):
  f16*   WcT_hi = (f16*)(ws);                       //     98,304
  f16*   WcT_lo = (f16*)(ws + 98304);               //     98,304
  float* bc     = (float*)(ws + 116969472);         //        256
  float* h1     = (float*)(ws + 116969728);         //  4,423,680
  float* coords = (float*)(ws + 121393408);         //    147,456  (total 121,540,864)

  cast_x_kernel<<<dim3(M_TOT * ND / 1024), dim3(256), 0, stream>>>(x, xb);
  cast_w_kernel<<<dim3(N_TOT * ND / 256), dim3(256), 0, stream>>>(Wq, Wk, Wv, WT);
  gemm_kernel<<<dim3((M_TOT / 128) * (N_TOT / 128)), dim3(256), 0, stream>>>(xb, WT, bq, bk, bv, qkv);
  wcT_kernel<<<dim3(193), dim3(256), 0, stream>>>(Wq, Wk, bq, bk, W1, b1, WcT_hi, WcT_lo, bc);
  z1_mfma_kernel<<<dim3(M_TOT / 64), dim3(256), 0, stream>>>(x, WcT_hi, WcT_lo, bc, h1);
  mlp_tail_kernel<<<dim3(M_TOT / 4), dim3(256), 0, stream>>>(h1, W2, b2, W3, b3, coords);
  sample_kernel<<<dim3(M_TOT), dim3(256), 0, stream>>>(qkv, coords, out);
  (void)in_sizes; (void)n_in; (void)out_size; (void)ws_size;
}